// Round 5
// baseline (232.151 us; speedup 1.0000x reference)
//
#include <hip/hip_runtime.h>

// Problem constants (fixed in the reference file)
#define OHh   60
#define OWw   60
#define NBINS (OHh * OWw)   // 3600
#define NB    64            // batches
#define NS    4096          // spikes per batch
#define CAP   128

#define NW     4            // waves per block
#define SEG    (NS / NW)    // 1024 spikes scanned per wave
#define CH     (SEG / 64)   // 16 chunks per wave
#define WSLOTS 40           // staged slots per wave-segment per bin (+1 dummy row)
#define PRE0   64           // slots [PRE0, CAP) prefilled -1 during scan
#define REPS   3            // R13 DIAGNOSTIC: run the proven R8 body 3x so the
                            // kernel (~97-145 us) lands in the top-5 PMC rows.
                            // Reps are idempotent (identical output rewritten).
                            // Warm reps (1,2) see L2-resident output sectors ->
                            // no write-allocate RMW fetch -> dur separates
                            // fetch-bound (W~25) from stall-bound (W~48).

// R13 = R8 structure byte-for-byte (148.9 us this session), wrapped in a
// 3-rep loop. R10/R11/R12 all landed at 153.6 +- 0.1 despite attacking
// writes (x2) and scan LDS -> model is wrong; R9's PMC row (FETCH 830 MB
// vs 64 MB inputs, Occ 24% vs 87% static) left two live hypotheses that
// demand opposite fixes. This round buys the R8-structure's own counters.
__global__ __launch_bounds__(256) void sort_spikes_row4(
    const int* __restrict__ spikes, int* __restrict__ out) {
    const int bid  = (int)blockIdx.x;
    const int b    = bid & (NB - 1);   // batch-minor -> batch b pinned to XCD b%8
    const int row  = bid >> 6;         // output row oh, 0..59
    const int tid  = (int)threadIdx.x;
    const int wv   = tid >> 6;
    const int lane = tid & 63;
    const bool valid  = lane < OWw;
    const int  lane_c = valid ? lane : 127;  // parked lanes: window test auto-fails

    __shared__ short          stage[NW][WSLOTS + 1][64];  // 20992 B (+1 dummy sink)
    __shared__ unsigned short hits[NW][64];               // compacted chunk payloads
    __shared__ int            cnt[NW][64];
    __shared__ int            ovf;                        // ~22.5 KB -> 7 blocks/CU

    if (tid == 0) ovf = 0;

    const int* __restrict__ sp   = spikes + b * NS + wv * SEG;
    int* __restrict__       outb = out + (size_t)b * (CAP * NBINS) + row * OWw;

    // Issue all 16 chunk loads up front (deep vmcnt pipeline; L2-resident
    // after the first of a batch's 60 blocks touches them).
    int vs[CH];
#pragma unroll
    for (int c = 0; c < CH; ++c) vs[c] = sp[c * 64 + lane];

    unsigned short* const hitbuf      = &hits[wv][0];
    short* const          stage_lane  = &stage[wv][0][lane];      // + count*64 shorts
    short* const          stage_dummy = &stage[wv][WSLOTS][lane]; // sink row

    for (int rep = 0; rep < REPS; ++rep) {
        int count = 0;
#pragma unroll
        for (int c = 0; c < CH; ++c) {
            int v = vs[c];
            asm volatile("" : "+v"(v));  // freshness: defeat cross-rep CSE of
                                         // kh/mask/ballot so warm reps do full work
            const int kh  = ((v >> 6) & 63) - row;
            const bool halo = (unsigned)kh < 5u;
            const int w   = v & 63;
            const int A   = (v >> 12) * 25 + kh * 5 + w;  // ckk_base + w, 10 bits
            const unsigned short P = (unsigned short)((w << 10) | A);

            const unsigned long long mask = __ballot(halo);   // wave-uniform
            const int pos = __builtin_amdgcn_mbcnt_hi(
                (unsigned)(mask >> 32),
                __builtin_amdgcn_mbcnt_lo((unsigned)mask, 0));  // rank among halo lanes
            if (halo) hitbuf[pos] = P;                          // s-order preserved
            const int n = __popcll(mask);                       // uniform

            for (int i = 0; i < n; ++i) {            // uniform trip count
                const int Pj  = (int)hitbuf[i];      // ds_read_u16 broadcast
                const int kw  = (Pj >> 10) - lane_c; // per-lane window offset
                const bool inwin = (unsigned)kw < 5u;
                const int val = (Pj & 0x3ff) - lane_c;           // == ckk when inwin
                short* a = (inwin & (count < WSLOTS))
                               ? (stage_lane + count * 64)       // count*128 B
                               : stage_dummy;
                *a = (short)val;                      // garbage to sink is fine
                count += inwin;
            }

            // Hidden write: one -1 slot-row per chunk -> slots [64,128) done by
            // scan end (wv*CH+c spans 0..63). Contiguous 240 B run.
            if (valid) outb[(PRE0 + wv * CH + c) * NBINS + lane] = -1;
        }
        cnt[wv][lane] = count;
        if (__ballot(count > WSLOTS) && lane == 0) ovf = 1;  // benign multi-write
        __syncthreads();

        if (ovf == 0) {
            if (valid) {
                const int c0 = cnt[0][lane], c1 = cnt[1][lane];
                const int c2 = cnt[2][lane], c3 = cnt[3][lane];
                const int o1 = c0, o2 = c0 + c1, o3 = o2 + c2;
                const int total = o3 + c3;                 // <=160
                // Dump slots [0,64): 16 per wave, wave order == s order.
#pragma unroll 4
                for (int i = 0; i < PRE0 / NW; ++i) {
                    const int k = wv * (PRE0 / NW) + i;
                    int val = -1;
                    if (k < total) {
                        int wsel = 0, base = 0;
                        if (k >= o1) { wsel = 1; base = o1; }
                        if (k >= o2) { wsel = 2; base = o2; }
                        if (k >= o3) { wsel = 3; base = o3; }
                        val = (int)stage[wsel][k - base][lane];  // 2-way banks, free
                    }
                    outb[k * NBINS + lane] = val;          // contiguous 240 B run
                }
                // Astronomically rare: overwrite prefilled -1s with real values.
                for (int k = PRE0 + wv; k < total && k < CAP; k += NW) {
                    int wsel = 0, base = 0;
                    if (k >= o1) { wsel = 1; base = o1; }
                    if (k >= o2) { wsel = 2; base = o2; }
                    if (k >= o3) { wsel = 3; base = o3; }
                    outb[k * NBINS + lane] = (int)stage[wsel][k - base][lane];
                }
            }
        } else if (wv == 0) {
            // Fallback: >40 staged hits in one bin from one 1024-spike segment
            // (P ~ 1e-22 random input). Serial redo, direct global stores.
            const int* __restrict__ spf = spikes + b * NS;
            int cc = 0;
            for (int c = 0; c < NS / 64; ++c) {
                const int v = spf[c * 64 + lane];
                const int h = (v >> 6) & 63;
                unsigned long long mask = __ballot((unsigned)(h - row) < 5u);
                while (mask) {
                    const int j = (int)__builtin_ctzll(mask);
                    mask &= mask - 1;
                    const int vj =
                        __builtin_amdgcn_readlane(v, __builtin_amdgcn_readfirstlane(j));
                    const int wj  = vj & 63;
                    const int khj = ((vj >> 6) & 63) - row;
                    const int cj  = vj >> 12;
                    const int kw  = wj - lane;
                    if (((unsigned)kw < 5u) & valid) {
                        if (cc < CAP)
                            outb[cc * NBINS + lane] = cj * 25 + khj * 5 + kw;
                        ++cc;
                    }
                }
            }
            if (valid)
                for (int k = cc; k < CAP; ++k) outb[k * NBINS + lane] = -1;
        }
        __syncthreads();  // next rep's scan overwrites stage read by this dump
    }
}

extern "C" void kernel_launch(void* const* d_in, const int* in_sizes, int n_in,
                              void* d_out, int out_size, void* d_ws, size_t ws_size,
                              hipStream_t stream) {
    const int* spikes = (const int*)d_in[0];  // (B, S, 1, 1) int32
    // d_in[1] (indices table) unused: membership is pure arithmetic.
    int* out = (int*)d_out;                   // (B, CAP, OH, OW) int32

    dim3 grid(OHh * NB);                      // 3840 blocks, batch-minor
    dim3 block(256);                          // 4 waves/block
    sort_spikes_row4<<<grid, block, 0, stream>>>(spikes, out);
}

// Round 6
// 142.693 us; speedup vs baseline: 1.6269x; 1.6269x over previous
//
#include <hip/hip_runtime.h>

// Problem constants (fixed in the reference file)
#define OHh   60
#define OWw   60
#define NBINS (OHh * OWw)   // 3600
#define NB    64            // batches
#define NS    4096          // spikes per batch
#define CAP   128

#define NW     4            // waves per block
#define SEG    (NS / NW)    // 1024 spikes scanned per wave
#define CH     (SEG / 64)   // 16 chunks per wave
#define WSLOTS 38           // real slots per (wave,bin); slot 38 = min-clamp sink
                            // (per-(wave,bin) ~ Poisson(6.25); P(>38) ~ 1e-18)
#define PRE0   64           // slots [PRE0, CAP) prefilled -1 during scan
                            // (per-bin total ~ Poisson(25); P(>64) ~ 1e-11)

// One 4-wave block per (batch, output row); lane == ow (lanes 60..63 parked).
// R13 diagnostic (3-rep, PMC-visible): the R8 structure is VALU-ISSUE-bound
// (VALUBusy 70.5%, ~31 us of 44 us/rep); FETCH 461 MB/rep is L3-served RMW
// and NOT limiting (warm reps == cold reps -> R10/R11 alignment nulls
// explained); WRITE 0.95x output; bank conflicts ~5%. R14 keeps the R8
// structure byte-for-byte and cuts inner-loop VALU ~40%:
//  (1) D-trick: hit staged as R=(w<<16)|A; D = R - lane*65537 yields
//      kw = D>>16 and ckk = D&0xffff in ONE sub. Cross-half borrow only
//      when A<lane => w<lane => test fails anyway. ds_write_b16 stores
//      D's low half directly (no val extraction).
//  (2) min-clamp slot: garbage writes from non-inwin lanes go to slot
//      `count`, overwritten by the next inwin hit (count monotone; dump
//      reads only slots < count). Replaces cmp+cndmask dummy select.
//  (3) ds_read_b64 pairs: 1 LDS read per 2 hits; odd tail masked by a
//      wave-uniform predicate.
// Dump, prefill pacing, batch-minor grid, fallback: unchanged from R8.
__global__ __launch_bounds__(256) void sort_spikes_row4(
    const int* __restrict__ spikes, int* __restrict__ out) {
    const int bid  = (int)blockIdx.x;
    const int b    = bid & (NB - 1);   // batch-minor -> batch b pinned to XCD b%8
    const int row  = bid >> 6;         // output row oh, 0..59
    const int tid  = (int)threadIdx.x;
    const int wv   = tid >> 6;
    const int lane = tid & 63;
    const bool valid  = lane < OWw;
    const int  lane_c = valid ? lane : 127;  // parked lanes: window test auto-fails
    const int  lane_k = lane_c * 65537;      // subtracts lane from BOTH halves of R

    __shared__ short stage[NW][WSLOTS + 1][64];  // 19968 B (+1 sink row via min)
    __shared__ __align__(8) int hits[NW][64];    // 1024 B (b32 records, b64 pair reads)
    __shared__ int   cnt[NW][64];                // 1024 B
    __shared__ int   ovf;                        // total ~22.0 KB -> 7 blocks/CU

    if (tid == 0) ovf = 0;

    const int* __restrict__ sp   = spikes + b * NS + wv * SEG;
    int* __restrict__       outb = out + (size_t)b * (CAP * NBINS) + row * OWw;

    // Issue all 16 chunk loads up front (deep vmcnt pipeline; L2-resident
    // after the first of a batch's 60 blocks touches them).
    int vs[CH];
#pragma unroll
    for (int c = 0; c < CH; ++c) vs[c] = sp[c * 64 + lane];

    int* const   hitbuf     = &hits[wv][0];
    short* const stage_lane = &stage[wv][0][lane];   // + slot*64 shorts (128 B)

    const int row5 = row * 5;

    int count = 0;
#pragma unroll
    for (int c = 0; c < CH; ++c) {
        const int v  = vs[c];
        const int h  = (v >> 6) & 63;
        const int w  = v & 63;
        // A = c*25 + kh*5 + w = ckk_base + w; in [0,859) when halo.
        const int A  = (v >> 12) * 25 + h * 5 + w - row5;
        const int R  = (w << 16) | A;            // halo-only values enter hitbuf
        const bool halo = (unsigned)(h - row) < 5u;

        const unsigned long long mask = __ballot(halo);   // wave-uniform
        const int pos = __builtin_amdgcn_mbcnt_hi(
            (unsigned)(mask >> 32),
            __builtin_amdgcn_mbcnt_lo((unsigned)mask, 0));  // rank among halo lanes
        if (halo) hitbuf[pos] = R;                          // s-order preserved
        const int n = __popcll(mask);                       // uniform (SALU)

        // Hidden write: one -1 slot-row per chunk -> slots [64,128) done by
        // scan end (wv*CH+c spans 0..63). Contiguous 240 B run, paced under scan.
        if (valid) outb[(PRE0 + wv * CH + c) * NBINS + lane] = -1;

        for (int i = 0; i < n; i += 2) {         // uniform trip count (~5 hits/chunk)
            const int2 RR = *(const int2*)&hitbuf[i];       // ds_read_b64: 2 hits
            // hit i (earlier in s order)
            const int  D0 = RR.x - lane_k;       // hi: w-lane (kw), lo: A-lane (ckk)
            const bool t0 = (unsigned)(D0 >> 16) < 5u;
            stage_lane[min(count, WSLOTS) * 64] = (short)D0;  // b16 stores low half
            count += t0;
            // hit i+1 (masked off on odd tail; n is wave-uniform)
            const int  D1 = RR.y - lane_k;
            const bool t1 = ((unsigned)(D1 >> 16) < 5u) & (i + 1 < n);
            stage_lane[min(count, WSLOTS) * 64] = (short)D1;
            count += t1;
        }
    }
    cnt[wv][lane] = count;
    if (__ballot(count > WSLOTS) && lane == 0) ovf = 1;  // benign multi-write
    __syncthreads();

    if (ovf == 0) {
        if (valid) {
            const int c0 = cnt[0][lane], c1 = cnt[1][lane];
            const int c2 = cnt[2][lane], c3 = cnt[3][lane];
            const int o1 = c0, o2 = c0 + c1, o3 = o2 + c2;
            const int total = o3 + c3;                 // <=152
            // Dump slots [0,64): 16 per wave, wave order == s order.
#pragma unroll 4
            for (int i = 0; i < PRE0 / NW; ++i) {
                const int k = wv * (PRE0 / NW) + i;
                int val = -1;
                if (k < total) {
                    int wsel = 0, base = 0;
                    if (k >= o1) { wsel = 1; base = o1; }
                    if (k >= o2) { wsel = 2; base = o2; }
                    if (k >= o3) { wsel = 3; base = o3; }
                    val = (int)stage[wsel][k - base][lane];  // bank=lane>>1, 2-way free
                }
                outb[k * NBINS + lane] = val;          // contiguous 240 B run
            }
            // Astronomically rare: overwrite prefilled -1s with real values.
            for (int k = PRE0 + wv; k < total && k < CAP; k += NW) {
                int wsel = 0, base = 0;
                if (k >= o1) { wsel = 1; base = o1; }
                if (k >= o2) { wsel = 2; base = o2; }
                if (k >= o3) { wsel = 3; base = o3; }
                outb[k * NBINS + lane] = (int)stage[wsel][k - base][lane];
            }
        }
    } else if (wv == 0) {
        // Fallback: >38 staged hits in one bin from one 1024-spike segment
        // (P ~ 1e-13/launch random input). Serial redo, direct global stores.
        const int* __restrict__ spf = spikes + b * NS;
        int cc = 0;
        for (int c = 0; c < NS / 64; ++c) {
            const int v = spf[c * 64 + lane];
            const int h = (v >> 6) & 63;
            unsigned long long mask = __ballot((unsigned)(h - row) < 5u);
            while (mask) {
                const int j = (int)__builtin_ctzll(mask);
                mask &= mask - 1;
                const int vj =
                    __builtin_amdgcn_readlane(v, __builtin_amdgcn_readfirstlane(j));
                const int wj  = vj & 63;
                const int khj = ((vj >> 6) & 63) - row;
                const int cj  = vj >> 12;
                const int kw  = wj - lane;
                if (((unsigned)kw < 5u) & valid) {
                    if (cc < CAP)
                        outb[cc * NBINS + lane] = cj * 25 + khj * 5 + kw;
                    ++cc;
                }
            }
        }
        if (valid)
            for (int k = cc; k < CAP; ++k) outb[k * NBINS + lane] = -1;
    }
}

extern "C" void kernel_launch(void* const* d_in, const int* in_sizes, int n_in,
                              void* d_out, int out_size, void* d_ws, size_t ws_size,
                              hipStream_t stream) {
    const int* spikes = (const int*)d_in[0];  // (B, S, 1, 1) int32
    // d_in[1] (indices table) unused: membership is pure arithmetic.
    int* out = (int*)d_out;                   // (B, CAP, OH, OW) int32

    dim3 grid(OHh * NB);                      // 3840 blocks, batch-minor
    dim3 block(256);                          // 4 waves/block
    sort_spikes_row4<<<grid, block, 0, stream>>>(spikes, out);
}

// Round 8
// 138.089 us; speedup vs baseline: 1.6812x; 1.0333x over previous
//
#include <hip/hip_runtime.h>

// Problem constants (fixed in the reference file)
#define OHh   60
#define OWw   60
#define NBINS (OHh * OWw)   // 3600
#define NB    64            // batches
#define NS    4096          // spikes per batch
#define CAP   128

#define NW     4            // waves per block
#define SEG    (NS / NW)    // 1024 spikes scanned per wave
#define CH     (SEG / 64)   // 16 chunks per wave
#define HCAP   160          // hit-list cap per wave (lambda ~80, +9 sigma; 5 mask dwords)
#define PRE0   64           // slots [PRE0, CAP) prefilled -1 during scan
                            // (per-bin total ~ Poisson(25); P(>64) ~ 1e-11)

// One 4-wave block per (batch, output row); lane == ow (lanes 60..63 parked).
// R15 (resubmit -- R7 attempt died to container infra, no GPU result):
// R13/R14 established the kernel is instruction-issue-bound (VALUBusy 70%);
// R14's cheaper broadcast won exactly as predicted. The broadcast loop is
// still ~55% of issue (64 lanes x ~5.5 VALU/hit, ~5 winners). R15 goes
// hit-parallel (12 hits x 5 window-lanes, R9's decomposition) but WITHOUT
// R9's fatal per-bin count RMW chain: each hit has a unique s-ordered index
// src in the wave's hit list, so the scatter just sets bit src in a
// per-(wave,bin) 160-bit presence mask via ds_or_b32 (no-return LDS atomic,
// commutative, chain-free; stride 7 dwords = bank-conflict-free). The dump
// reconstructs order: lane=bin iterates its own masks ascending (= s-order),
// gathers ckk from the hit list, scatters into LDS outimg[64][60] at
// k = cross-wave prefix + rank; then all waves stream outimg rows out in the
// proven contiguous-240B pattern. Per-bin overflow is now IMPOSSIBLE (all
// 160 hits representable) -- only hbase>160 (P~1e-50) falls back. Prefill
// of slots [64,128) stays paced under the scan (proven R8 pattern).
__global__ __launch_bounds__(256) void sort_spikes_row4(
    const int* __restrict__ spikes, int* __restrict__ out) {
    const int bid  = (int)blockIdx.x;
    const int b    = bid & (NB - 1);   // batch-minor -> batch b pinned to XCD b%8
    const int row  = bid >> 6;         // output row oh, 0..59
    const int tid  = (int)threadIdx.x;
    const int wv   = tid >> 6;
    const int lane = tid & 63;
    const bool valid = lane < OWw;

    __shared__ int            hitbuf[NW][256];    // 4096 B (u32 hit records)
    __shared__ unsigned       pres[NW][64][7];    // 7168 B (5 dwords used; stride 7
                                                  //  is coprime 32 -> bank-free)
    __shared__ unsigned short outimg[PRE0][OWw];  // 7680 B  [k][ow] staging image
    __shared__ int            cnt[NW][64];        // 1024 B
    __shared__ int            ovf;                // total ~19.5 KB -> 8 blocks/CU

    if (tid == 0) ovf = 0;
#pragma unroll
    for (int i = 0; i < 5; ++i) pres[wv][lane][i] = 0u;  // own-wave region only

    {   // outimg := all 0xFFFF (-1 rows); 1920 dwords across 256 threads
        int* oi = (int*)&outimg[0][0];
        for (int i = tid; i < PRE0 * OWw / 2; i += 256) oi[i] = -1;
    }

    const int* __restrict__ sp   = spikes + b * NS + wv * SEG;
    int* __restrict__       outb = out + (size_t)b * (CAP * NBINS) + row * OWw;

    // Issue all 16 chunk loads up front (deep vmcnt pipeline; L2-resident
    // after the first of a batch's 60 blocks touches them).
    int vs[CH];
#pragma unroll
    for (int c = 0; c < CH; ++c) vs[c] = sp[c * 64 + lane];

    int* const hb_w = &hitbuf[wv][0];
    const int row5 = row * 5;

    // ---- Phase 1: collect this wave's halo hits, s-ordered, as u32 records
    //      R = (w<<16) | A with A = ckk_base + w (so ckk(bin) = A - bin). ----
    int hbase = 0;
#pragma unroll
    for (int c = 0; c < CH; ++c) {
        const int v = vs[c];
        const int h = (v >> 6) & 63;
        const int w = v & 63;
        const int A = (v >> 12) * 25 + h * 5 + w - row5;  // >=0 for halo hits
        const int R = (w << 16) | A;
        const bool halo = (unsigned)(h - row) < 5u;

        const unsigned long long mask = __ballot(halo);   // wave-uniform
        const int pos = __builtin_amdgcn_mbcnt_hi(
            (unsigned)(mask >> 32),
            __builtin_amdgcn_mbcnt_lo((unsigned)mask, 0));
        if (halo) hb_w[min(hbase + pos, 255)] = R;        // s-order preserved
        hbase += (int)__popcll(mask);                     // uniform

        // Hidden write: one -1 slot-row per chunk -> slots [64,128) done by
        // scan end (wv*CH+c spans 0..63). Contiguous 240 B run, paced.
        if (valid) outb[(PRE0 + wv * CH + c) * NBINS + lane] = -1;
    }
    if (hbase > HCAP && lane == 0) ovf = 1;   // truncated list (P ~ 1e-50)
    const int n = min(hbase, HCAP);           // wave-uniform

    // ---- Phase 2: hit-parallel presence scatter, 12 hits x 5 kw-lanes. ----
    const int qi  = (lane < OWw) ? (lane / 5) : 4096;  // parked: hidx>=n always
    const int kwc = lane - qi * 5;
    for (int hbi = 0; hbi < n; hbi += 12) {            // uniform trip (~7 iters)
        const int hidx = hbi + qi;
        const int R    = hb_w[min(hidx, 255)];         // 5-lane shared-addr read
        const int bin  = (R >> 16) - kwc;              // this lane's candidate ow
        if (((unsigned)bin < 60u) && (hidx < n)) {     // exec-masked atomic
            atomicOr(&pres[wv][bin][hidx >> 5], 1u << (hidx & 31));
        }
    }

    // Own-bin count (atomics above are same-wave -> DS-pipe program order).
    unsigned m0 = pres[wv][lane][0], m1 = pres[wv][lane][1];
    unsigned m2 = pres[wv][lane][2], m3 = pres[wv][lane][3];
    unsigned m4 = pres[wv][lane][4];
    cnt[wv][lane] = __builtin_popcount(m0) + __builtin_popcount(m1) +
                    __builtin_popcount(m2) + __builtin_popcount(m3) +
                    __builtin_popcount(m4);
    __syncthreads();

    if (ovf == 0) {
        // ---- Phase 3: order reconstruction. lane = bin; iterate own wave's
        //      mask ascending (= s-order), scatter ckk into outimg at
        //      k = prefix(earlier waves) + rank. ----
        if (valid) {
            int k = 0;
            for (int w = 0; w < wv; ++w) k += cnt[w][lane];  // cross-wave prefix
            unsigned mw[5] = {m0, m1, m2, m3, m4};
#pragma unroll
            for (int wd = 0; wd < 5; ++wd) {
                unsigned mm = mw[wd];
                while (mm) {                       // divergent; wall = max count
                    const int j = __builtin_ctz(mm);
                    mm &= mm - 1;
                    const int src = wd * 32 + j;
                    const int ck  = (hb_w[src] & 0xffff) - lane;  // ckk gather
                    if (k < PRE0) outimg[k][lane] = (unsigned short)ck;
                    else if (k < CAP) outb[k * NBINS + lane] = ck;  // P ~ 1e-11
                    ++k;
                }
            }
        }
        __syncthreads();
        // ---- Phase 4: stream outimg -> global, 16 rows per wave, the proven
        //      contiguous-240B-run pattern (k-major, lane = ow). ----
        if (valid) {
#pragma unroll 4
            for (int i = 0; i < PRE0 / NW; ++i) {
                const int kk = wv * (PRE0 / NW) + i;
                outb[kk * NBINS + lane] = (int)(short)outimg[kk][lane];
            }
        }
    } else if (wv == 0) {
        // Fallback (P ~ 1e-50): serial redo, direct global stores.
        const int* __restrict__ spf = spikes + b * NS;
        int cc = 0;
        for (int c = 0; c < NS / 64; ++c) {
            const int v = spf[c * 64 + lane];
            const int h = (v >> 6) & 63;
            unsigned long long mask = __ballot((unsigned)(h - row) < 5u);
            while (mask) {
                const int j = (int)__builtin_ctzll(mask);
                mask &= mask - 1;
                const int vj =
                    __builtin_amdgcn_readlane(v, __builtin_amdgcn_readfirstlane(j));
                const int wj  = vj & 63;
                const int khj = ((vj >> 6) & 63) - row;
                const int cj  = vj >> 12;
                const int kw  = wj - lane;
                if (((unsigned)kw < 5u) & valid) {
                    if (cc < CAP)
                        outb[cc * NBINS + lane] = cj * 25 + khj * 5 + kw;
                    ++cc;
                }
            }
        }
        if (valid)
            for (int k = cc; k < CAP; ++k) outb[k * NBINS + lane] = -1;
    }
}

extern "C" void kernel_launch(void* const* d_in, const int* in_sizes, int n_in,
                              void* d_out, int out_size, void* d_ws, size_t ws_size,
                              hipStream_t stream) {
    const int* spikes = (const int*)d_in[0];  // (B, S, 1, 1) int32
    // d_in[1] (indices table) unused: membership is pure arithmetic.
    int* out = (int*)d_out;                   // (B, CAP, OH, OW) int32

    dim3 grid(OHh * NB);                      // 3840 blocks, batch-minor
    dim3 block(256);                          // 4 waves/block
    sort_spikes_row4<<<grid, block, 0, stream>>>(spikes, out);
}